// Round 1
// baseline (500.168 us; speedup 1.0000x reference)
//
#include <hip/hip_runtime.h>
#include <math.h>

#define N_ROWS 131072
#define D_COLS 512
#define TOTAL4 (N_ROWS * D_COLS / 4)   // 16777216 float4 elements

// Pass 1: per-thread sum / sumsq over a loop-invariant column quad, then
// block-level LDS reduction -> per-block partial sums in d_ws.
// Block = 512 threads; grid stride (= gridDim*512) is a multiple of 128
// float4s, so thread t always owns columns 4*(t%128)..+3.
__global__ void bn_stats_kernel(const float4* __restrict__ X,
                                float* __restrict__ partial) {
    const int t = threadIdx.x;
    const int g = blockIdx.x * blockDim.x + t;
    const int stride = gridDim.x * blockDim.x;

    float4 s = make_float4(0.f, 0.f, 0.f, 0.f);
    float4 q = make_float4(0.f, 0.f, 0.f, 0.f);

    for (int i = g; i < TOTAL4; i += stride) {
        float4 x = X[i];
        s.x += x.x; s.y += x.y; s.z += x.z; s.w += x.w;
        q.x = fmaf(x.x, x.x, q.x);
        q.y = fmaf(x.y, x.y, q.y);
        q.z = fmaf(x.z, x.z, q.z);
        q.w = fmaf(x.w, x.w, q.w);
    }

    __shared__ float4 ls[512];
    __shared__ float4 lq[512];
    ls[t] = s;
    lq[t] = q;
    __syncthreads();

    if (t < 256) {
        float4 a = ls[t + 256], b = lq[t + 256];
        ls[t].x += a.x; ls[t].y += a.y; ls[t].z += a.z; ls[t].w += a.w;
        lq[t].x += b.x; lq[t].y += b.y; lq[t].z += b.z; lq[t].w += b.w;
    }
    __syncthreads();
    if (t < 128) {
        float4 a = ls[t + 128], b = lq[t + 128];
        float4 sv = ls[t], qv = lq[t];
        sv.x += a.x; sv.y += a.y; sv.z += a.z; sv.w += a.w;
        qv.x += b.x; qv.y += b.y; qv.z += b.z; qv.w += b.w;
        // layout per block: sum[512] then sumsq[512]
        float* dst = partial + (size_t)blockIdx.x * 1024;
        *(float4*)(dst + 4 * t)       = sv;
        *(float4*)(dst + 512 + 4 * t) = qv;
    }
}

// Pass 1b: one block per column d. Reduce B per-block partials, emit
// scale[d] = gamma*rsqrt(var), bias[d] = beta - mean*scale.
__global__ void bn_finalize_kernel(const float* __restrict__ partial,
                                   const float* __restrict__ gamma,
                                   const float* __restrict__ beta,
                                   float* __restrict__ scale,
                                   float* __restrict__ bias,
                                   int B) {
    const int d = blockIdx.x;
    const int t = threadIdx.x;

    float s = 0.f, q = 0.f;
    for (int b = t; b < B; b += blockDim.x) {
        s += partial[(size_t)b * 1024 + d];
        q += partial[(size_t)b * 1024 + 512 + d];
    }

    __shared__ float ls[256];
    __shared__ float lq[256];
    ls[t] = s;
    lq[t] = q;
    __syncthreads();
    for (int off = 128; off > 0; off >>= 1) {
        if (t < off) { ls[t] += ls[t + off]; lq[t] += lq[t + off]; }
        __syncthreads();
    }

    if (t == 0) {
        const float invN = 1.0f / (float)N_ROWS;
        float mean = ls[0] * invN;
        float var  = lq[0] * invN - mean * mean;   // no epsilon, per reference
        float inv  = rsqrtf(var);
        float sc   = gamma[d] * inv;
        scale[d] = sc;
        bias[d]  = beta[d] - mean * sc;
    }
}

// Pass 2: Y = X*scale + bias. Column quad is loop-invariant per thread
// (stride multiple of 128 float4s) so scale/bias load once.
__global__ void bn_norm_kernel(const float4* __restrict__ X,
                               float4* __restrict__ Y,
                               const float* __restrict__ scale,
                               const float* __restrict__ bias) {
    const int g = blockIdx.x * blockDim.x + threadIdx.x;
    const int stride = gridDim.x * blockDim.x;
    const int c = (g & 127) * 4;

    const float4 sc = *(const float4*)(scale + c);
    const float4 bi = *(const float4*)(bias + c);

    for (int i = g; i < TOTAL4; i += stride) {
        float4 x = X[i];
        float4 y;
        y.x = fmaf(x.x, sc.x, bi.x);
        y.y = fmaf(x.y, sc.y, bi.y);
        y.z = fmaf(x.z, sc.z, bi.z);
        y.w = fmaf(x.w, sc.w, bi.w);
        Y[i] = y;
    }
}

extern "C" void kernel_launch(void* const* d_in, const int* in_sizes, int n_in,
                              void* d_out, int out_size, void* d_ws, size_t ws_size,
                              hipStream_t stream) {
    const float* X     = (const float*)d_in[0];
    const float* gamma = (const float*)d_in[1];
    const float* beta  = (const float*)d_in[2];
    float* Y  = (float*)d_out;
    float* ws = (float*)d_ws;

    // Fit partials in workspace: B blocks * 1024 floats + 1024 floats scale/bias.
    int B = 512;
    while (B > 64 && ((size_t)B * 1024 + 1024) * sizeof(float) > ws_size) B >>= 1;

    float* partial = ws;
    float* scale   = ws + (size_t)B * 1024;
    float* bias    = scale + 512;

    bn_stats_kernel<<<B, 512, 0, stream>>>((const float4*)X, partial);
    bn_finalize_kernel<<<512, 256, 0, stream>>>(partial, gamma, beta, scale, bias, B);
    bn_norm_kernel<<<2048, 256, 0, stream>>>((const float4*)X, (float4*)Y, scale, bias);
}

// Round 2
// 478.175 us; speedup vs baseline: 1.0460x; 1.0460x over previous
//
#include <hip/hip_runtime.h>
#include <math.h>

#define N_ROWS 131072
#define D_COLS 512
#define TOTAL4 (N_ROWS * D_COLS / 4)   // 16777216 float4 elements

typedef float v4f __attribute__((ext_vector_type(4)));

// Pass 1: per-thread sum / sumsq over a loop-invariant column quad, then
// block-level LDS reduction -> per-block partial sums in d_ws.
// Block = 512 threads; grid stride (= gridDim*512) is a multiple of 128
// float4s, so thread t always owns columns 4*(t%128)..+3.
__global__ __launch_bounds__(512)
void bn_stats_kernel(const v4f* __restrict__ X, float* __restrict__ partial) {
    const int t = threadIdx.x;
    const int g = blockIdx.x * blockDim.x + t;
    const int stride = gridDim.x * blockDim.x;

    v4f s = (v4f)0.0f;
    v4f q = (v4f)0.0f;

    for (int i = g; i < TOTAL4; i += stride) {
        v4f x = X[i];
        s += x;
        q += x * x;
    }

    __shared__ v4f ls[512];
    __shared__ v4f lq[512];
    ls[t] = s;
    lq[t] = q;
    __syncthreads();

    if (t < 256) {
        ls[t] += ls[t + 256];
        lq[t] += lq[t + 256];
    }
    __syncthreads();
    if (t < 128) {
        v4f sv = ls[t] + ls[t + 128];
        v4f qv = lq[t] + lq[t + 128];
        // layout per block: sum[512] then sumsq[512]
        float* dst = partial + (size_t)blockIdx.x * 1024;
        *(v4f*)(dst + 4 * t)       = sv;
        *(v4f*)(dst + 512 + 4 * t) = qv;
    }
}

// Pass 1b: one block per column d. Reduce B per-block partials, emit
// scale[d] = gamma*rsqrt(var), bias[d] = beta - mean*scale.
__global__ __launch_bounds__(256)
void bn_finalize_kernel(const float* __restrict__ partial,
                        const float* __restrict__ gamma,
                        const float* __restrict__ beta,
                        float* __restrict__ scale,
                        float* __restrict__ bias,
                        int B) {
    const int d = blockIdx.x;
    const int t = threadIdx.x;

    float s = 0.f, q = 0.f;
    for (int b = t; b < B; b += blockDim.x) {
        s += partial[(size_t)b * 1024 + d];
        q += partial[(size_t)b * 1024 + 512 + d];
    }

    __shared__ float ls[256];
    __shared__ float lq[256];
    ls[t] = s;
    lq[t] = q;
    __syncthreads();
    for (int off = 128; off > 0; off >>= 1) {
        if (t < off) { ls[t] += ls[t + off]; lq[t] += lq[t + off]; }
        __syncthreads();
    }

    if (t == 0) {
        const float invN = 1.0f / (float)N_ROWS;
        float mean = ls[0] * invN;
        float var  = lq[0] * invN - mean * mean;   // no epsilon, per reference
        float inv  = rsqrtf(var);
        float sc   = gamma[d] * inv;
        scale[d] = sc;
        bias[d]  = beta[d] - mean * sc;
    }
}

// Pass 2: Y = X*scale + bias. Column quad is loop-invariant per thread
// (stride multiple of 128 float4s) so scale/bias load once.
// Y stores are non-temporal: Y is never re-read, and skipping cache
// allocation keeps X resident in L3 (X is exactly 256 MiB = L3 size).
__global__ __launch_bounds__(256)
void bn_norm_kernel(const v4f* __restrict__ X,
                    v4f* __restrict__ Y,
                    const float* __restrict__ scale,
                    const float* __restrict__ bias) {
    const int g = blockIdx.x * blockDim.x + threadIdx.x;
    const int stride = gridDim.x * blockDim.x;
    const int c = (g & 127) * 4;

    const v4f sc = *(const v4f*)(scale + c);
    const v4f bi = *(const v4f*)(bias + c);

    for (int i = g; i < TOTAL4; i += stride) {
        v4f x = X[i];
        v4f y = x * sc + bi;
        __builtin_nontemporal_store(y, &Y[i]);
    }
}

extern "C" void kernel_launch(void* const* d_in, const int* in_sizes, int n_in,
                              void* d_out, int out_size, void* d_ws, size_t ws_size,
                              hipStream_t stream) {
    const float* X     = (const float*)d_in[0];
    const float* gamma = (const float*)d_in[1];
    const float* beta  = (const float*)d_in[2];
    float* Y  = (float*)d_out;
    float* ws = (float*)d_ws;

    // Fit partials in workspace: B blocks * 1024 floats + 1024 floats scale/bias.
    int B = 512;
    while (B > 64 && ((size_t)B * 1024 + 1024) * sizeof(float) > ws_size) B >>= 1;

    float* partial = ws;
    float* scale   = ws + (size_t)B * 1024;
    float* bias    = scale + 512;

    bn_stats_kernel<<<B, 512, 0, stream>>>((const v4f*)X, partial);
    bn_finalize_kernel<<<512, 256, 0, stream>>>(partial, gamma, beta, scale, bias, B);
    bn_norm_kernel<<<4096, 256, 0, stream>>>((const v4f*)X, (v4f*)Y, scale, bias);
}